// Round 1
// baseline (766.320 us; speedup 1.0000x reference)
//
#include <hip/hip_runtime.h>
#include <math.h>

#define NB 512      // graph pairs
#define MM 64       // nodes per graph
#define DIN 32
#define EPGc 512    // edges per graph

// ----------------------------- GCN (fused 3 layers, per-graph in LDS) -----------------------------
template<int Fin, int Fout>
__device__ __forceinline__ void gcn_layer(
    const float* __restrict__ W, const float* __restrict__ bias,
    float* sh, float* st, float* so, float* sW,
    const int* sSrc, const int* sDst, const float* sDinv,
    float* __restrict__ outG, int g, bool relu_next)
{
  const int tid = threadIdx.x;
  for (int i = tid; i < Fin * Fout; i += 256) sW[i] = W[i];
  __syncthreads();
  // tmp = h @ W   (64 x Fout)
  for (int i = tid; i < MM * Fout; i += 256) {
    int n = i / Fout, f = i - n * Fout;
    float acc = 0.f;
#pragma unroll
    for (int k = 0; k < Fin; ++k) acc = fmaf(sh[n * Fin + k], sW[k * Fout + f], acc);
    st[i] = acc;
  }
  __syncthreads();
  // out = bias + self-loop contribution (dinv[n]^2)
  for (int i = tid; i < MM * Fout; i += 256) {
    int n = i / Fout;
    so[i] = bias[i - n * Fout] + st[i] * sDinv[n] * sDinv[n];
  }
  __syncthreads();
  // scatter edges: out[d] += tmp[s] * dinv[s]*dinv[d]
  for (int t = tid; t < EPGc * Fout; t += 256) {
    int e = t / Fout, f = t - e * Fout;
    int s = sSrc[e], d = sDst[e];
    atomicAdd(&so[d * Fout + f], st[s * Fout + f] * sDinv[s] * sDinv[d]);
  }
  __syncthreads();
  // store pre-relu feats, relu into sh for next layer
  for (int i = tid; i < MM * Fout; i += 256) {
    int n = i / Fout;
    float v = so[i];
    outG[(size_t)(g * MM + n) * Fout + (i - n * Fout)] = v;
    sh[i] = relu_next ? fmaxf(v, 0.f) : v;
  }
  __syncthreads();
}

__global__ __launch_bounds__(256) void gcn_kernel(
    const float* __restrict__ xq, const float* __restrict__ xc,
    const int* __restrict__ srcq, const int* __restrict__ dstq,
    const int* __restrict__ srcc, const int* __restrict__ dstc,
    const float* __restrict__ Wg0, const float* __restrict__ bg0,
    const float* __restrict__ Wg1, const float* __restrict__ bg1,
    const float* __restrict__ Wg2, const float* __restrict__ bg2,
    float* __restrict__ qf0, float* __restrict__ qf1, float* __restrict__ qf2,
    float* __restrict__ cf0, float* __restrict__ cf1, float* __restrict__ cf2)
{
  __shared__ __align__(16) float sh[4096];
  __shared__ __align__(16) float st[4096];
  __shared__ __align__(16) float so[4096];
  __shared__ float sW[2048];
  __shared__ int sSrc[EPGc], sDst[EPGc];
  __shared__ float sDinv[MM];
  __shared__ int sDeg[MM];

  const int g = blockIdx.x;
  const int which = blockIdx.y;
  const float* x = which ? xc : xq;
  const int* src = which ? srcc : srcq;
  const int* dst = which ? dstc : dstq;
  float* f0 = which ? cf0 : qf0;
  float* f1 = which ? cf1 : qf1;
  float* f2 = which ? cf2 : qf2;
  const int tid = threadIdx.x;

  if (tid < MM) sDeg[tid] = 1;  // self loop
  __syncthreads();
  for (int e = tid; e < EPGc; e += 256) {
    int s = src[g * EPGc + e] - g * MM;
    int d = dst[g * EPGc + e] - g * MM;
    sSrc[e] = s; sDst[e] = d;
    atomicAdd(&sDeg[d], 1);
  }
  __syncthreads();
  if (tid < MM) sDinv[tid] = rsqrtf((float)sDeg[tid]);
  // load x (64 x 32)
  for (int i = tid; i < MM * DIN; i += 256) sh[i] = x[(size_t)g * MM * DIN + i];
  __syncthreads();

  gcn_layer<32, 64>(Wg0, bg0, sh, st, so, sW, sSrc, sDst, sDinv, f0, g, true);
  gcn_layer<64, 32>(Wg1, bg1, sh, st, so, sW, sSrc, sDst, sDinv, f1, g, true);
  gcn_layer<32, 16>(Wg2, bg2, sh, st, so, sW, sSrc, sDst, sDinv, f2, g, false);
}

// ----------------------------- similarity: sim[b,m,n] = qf[b,m,:]·cf[b,n,:] -----------------------------
template<int F>
__global__ __launch_bounds__(256) void sim_kernel(
    const float* __restrict__ qf, const float* __restrict__ cf, float* __restrict__ sim)
{
  __shared__ __align__(16) float sq[64 * 68];
  __shared__ __align__(16) float sc[64 * 68];
  const int g = blockIdx.x, tid = threadIdx.x;
  for (int i = tid; i < 64 * F; i += 256) {
    int n = i / F, f = i - n * F;
    sq[n * 68 + f] = qf[(size_t)g * 64 * F + i];
    sc[n * 68 + f] = cf[(size_t)g * 64 * F + i];
  }
  __syncthreads();
  const int tm = (tid >> 4) << 2;  // 4 rows
  const int tn = (tid & 15) << 2;  // 4 cols
  float acc[4][4] = {};
  for (int k = 0; k < F; k += 4) {
    float4 aq[4], ac[4];
#pragma unroll
    for (int i = 0; i < 4; ++i) aq[i] = *reinterpret_cast<const float4*>(sq + (tm + i) * 68 + k);
#pragma unroll
    for (int j = 0; j < 4; ++j) ac[j] = *reinterpret_cast<const float4*>(sc + (tn + j) * 68 + k);
#pragma unroll
    for (int i = 0; i < 4; ++i)
#pragma unroll
      for (int j = 0; j < 4; ++j) {
        acc[i][j] = fmaf(aq[i].x, ac[j].x, acc[i][j]);
        acc[i][j] = fmaf(aq[i].y, ac[j].y, acc[i][j]);
        acc[i][j] = fmaf(aq[i].z, ac[j].z, acc[i][j]);
        acc[i][j] = fmaf(aq[i].w, ac[j].w, acc[i][j]);
      }
  }
#pragma unroll
  for (int i = 0; i < 4; ++i)
#pragma unroll
    for (int j = 0; j < 4; ++j)
      sim[(size_t)g * 4096 + (tm + i) * 64 + tn + j] = acc[i][j];
}

// ----------------------------- conv1 (1->8ch, 5x5, pad2) + relu + maxpool2 -----------------------------
__global__ __launch_bounds__(256) void conv1_kernel(
    const float* __restrict__ sim, const float* __restrict__ cw0,
    const float* __restrict__ cb0, int i_mat, float* __restrict__ p1)
{
  __shared__ float ss[68 * 69];  // 64x64 with halo 2, padded stride
  const int g = blockIdx.x, tid = threadIdx.x;
  for (int i = tid; i < 68 * 69; i += 256) ss[i] = 0.f;
  __syncthreads();
  for (int i = tid; i < 4096; i += 256) {
    int r = i >> 6, c = i & 63;
    ss[(r + 2) * 69 + (c + 2)] = sim[(size_t)g * 4096 + i];
  }
  __syncthreads();
  const float* __restrict__ w = cw0 + (size_t)i_mat * 8 * 25;
  const float* __restrict__ bb = cb0 + i_mat * 8;

  for (int it = 0; it < 4; ++it) {
    int pos = tid + (it << 8);           // pooled position in 32x32
    int y = pos >> 5, x = pos & 31;
    float win[6][6];
#pragma unroll
    for (int u = 0; u < 6; ++u)
#pragma unroll
      for (int v = 0; v < 6; ++v) win[u][v] = ss[(2 * y + u) * 69 + (2 * x + v)];
    float acc[8][4];
#pragma unroll
    for (int c = 0; c < 8; ++c) { acc[c][0] = 0; acc[c][1] = 0; acc[c][2] = 0; acc[c][3] = 0; }
#pragma unroll
    for (int u = 0; u < 5; ++u)
#pragma unroll
      for (int v = 0; v < 5; ++v) {
#pragma unroll
        for (int c = 0; c < 8; ++c) {
          float wt = w[c * 25 + u * 5 + v];   // uniform -> scalar load
          acc[c][0] = fmaf(win[u][v],     wt, acc[c][0]);
          acc[c][1] = fmaf(win[u][v + 1], wt, acc[c][1]);
          acc[c][2] = fmaf(win[u + 1][v], wt, acc[c][2]);
          acc[c][3] = fmaf(win[u + 1][v + 1], wt, acc[c][3]);
        }
      }
#pragma unroll
    for (int c = 0; c < 8; ++c) {
      float mx = fmaxf(fmaxf(acc[c][0], acc[c][1]), fmaxf(acc[c][2], acc[c][3])) + bb[c];
      p1[((size_t)g * 8 + c) * 1024 + pos] = fmaxf(mx, 0.f);
    }
  }
}

// ----------------------------- conv2 (8->16ch, 5x5, pad2) + relu + maxpool2 -> hcat -----------------------------
__global__ __launch_bounds__(256) void conv2_kernel(
    const float* __restrict__ p1, const float* __restrict__ cw1,
    const float* __restrict__ cb1, int i_mat, float* __restrict__ hcat)
{
  __shared__ float sh2[8 * 1332];  // 8 ch of 36x37 (32x32 + halo 2, padded stride)
  const int g = blockIdx.x, tid = threadIdx.x;
  for (int i = tid; i < 8 * 1332; i += 256) sh2[i] = 0.f;
  __syncthreads();
  for (int i = tid; i < 8192; i += 256) {
    int ic = i >> 10, rem = i & 1023;
    int r = rem >> 5, c = rem & 31;
    sh2[ic * 1332 + (r + 2) * 37 + (c + 2)] = p1[(size_t)g * 8192 + i];
  }
  __syncthreads();
  const float* __restrict__ w = cw1 + (size_t)i_mat * 3200;
  const float* __restrict__ bb = cb1 + i_mat * 16;
  const int ty = tid >> 4, tx = tid & 15;  // pooled position in 16x16

  float acc[16][4];
#pragma unroll
  for (int c = 0; c < 16; ++c) { acc[c][0] = 0; acc[c][1] = 0; acc[c][2] = 0; acc[c][3] = 0; }

  for (int ic = 0; ic < 8; ++ic) {
    float win[6][6];
#pragma unroll
    for (int u = 0; u < 6; ++u)
#pragma unroll
      for (int v = 0; v < 6; ++v) win[u][v] = sh2[ic * 1332 + (2 * ty + u) * 37 + (2 * tx + v)];
#pragma unroll
    for (int u = 0; u < 5; ++u)
#pragma unroll
      for (int v = 0; v < 5; ++v) {
#pragma unroll
        for (int c = 0; c < 16; ++c) {
          float wt = w[(c * 8 + ic) * 25 + u * 5 + v];  // uniform -> scalar load
          acc[c][0] = fmaf(win[u][v],     wt, acc[c][0]);
          acc[c][1] = fmaf(win[u][v + 1], wt, acc[c][1]);
          acc[c][2] = fmaf(win[u + 1][v], wt, acc[c][2]);
          acc[c][3] = fmaf(win[u + 1][v + 1], wt, acc[c][3]);
        }
      }
  }
#pragma unroll
  for (int c = 0; c < 16; ++c) {
    float mx = fmaxf(fmaxf(acc[c][0], acc[c][1]), fmaxf(acc[c][2], acc[c][3])) + bb[c];
    hcat[((size_t)g * 48 + i_mat * 16 + c) * 256 + tid] = fmaxf(mx, 0.f);
  }
}

// ----------------------------- linear 0: (512,12288)@(12288,256), split-K, atomic accumulate -----------------------------
__global__ __launch_bounds__(256) void init_l0(const float* __restrict__ bl0, float* __restrict__ l0)
{
  int i = blockIdx.x * 256 + threadIdx.x;   // 512*256
  l0[i] = bl0[i & 255];
}

__global__ __launch_bounds__(256) void lin0_kernel(
    const float* __restrict__ A, const float* __restrict__ Wl0, float* __restrict__ l0)
{
  __shared__ float sA[64][17];
  __shared__ float sB[16][65];
  const int rb = blockIdx.x * 64;       // 8 row blocks
  const int cb = blockIdx.y * 64;       // 4 col blocks
  const int k0 = blockIdx.z * 1536;     // 8 K splits
  const int tid = threadIdx.x;
  const int tx = tid & 15, ty = tid >> 4;
  float acc[4][4] = {};

  for (int kt = 0; kt < 1536; kt += 16) {
    {
      int r = (tid >> 4), k = tid & 15;
#pragma unroll
      for (int p = 0; p < 4; ++p)
        sA[r + p * 16][k] = A[(size_t)(rb + r + p * 16) * 12288 + k0 + kt + k];
    }
    {
      int kk = (tid >> 6), c = tid & 63;
#pragma unroll
      for (int p = 0; p < 4; ++p)
        sB[kk + p * 4][c] = Wl0[(size_t)(k0 + kt + kk + p * 4) * 256 + cb + c];
    }
    __syncthreads();
#pragma unroll
    for (int k = 0; k < 16; ++k) {
      float a[4], b[4];
#pragma unroll
      for (int i = 0; i < 4; ++i) a[i] = sA[ty * 4 + i][k];
#pragma unroll
      for (int j = 0; j < 4; ++j) b[j] = sB[k][tx * 4 + j];
#pragma unroll
      for (int i = 0; i < 4; ++i)
#pragma unroll
        for (int j = 0; j < 4; ++j) acc[i][j] = fmaf(a[i], b[j], acc[i][j]);
    }
    __syncthreads();
  }
#pragma unroll
  for (int i = 0; i < 4; ++i)
#pragma unroll
    for (int j = 0; j < 4; ++j)
      atomicAdd(&l0[(size_t)(rb + ty * 4 + i) * 256 + cb + tx * 4 + j], acc[i][j]);
}

// ----------------------------- head: relu -> lin1 -> relu -> score -> sigmoid -----------------------------
__global__ __launch_bounds__(64) void head_kernel(
    const float* __restrict__ l0, const float* __restrict__ Wl1, const float* __restrict__ bl1,
    const float* __restrict__ Wsc, const float* __restrict__ bsc, float* __restrict__ out)
{
  __shared__ float sr[256];
  const int b = blockIdx.x, j = threadIdx.x;
  for (int k = j; k < 256; k += 64) sr[k] = fmaxf(l0[(size_t)b * 256 + k], 0.f);
  __syncthreads();
  float acc = bl1[j];
  for (int k = 0; k < 256; ++k) acc = fmaf(sr[k], Wl1[k * 64 + j], acc);
  float v = fmaxf(acc, 0.f) * Wsc[j];
#pragma unroll
  for (int off = 32; off > 0; off >>= 1) v += __shfl_down(v, off);
  if (j == 0) out[b] = 1.f / (1.f + expf(-(v + bsc[0])));
}

// ----------------------------- launch -----------------------------
extern "C" void kernel_launch(void* const* d_in, const int* in_sizes, int n_in,
                              void* d_out, int out_size, void* d_ws, size_t ws_size,
                              hipStream_t stream)
{
  (void)in_sizes; (void)n_in; (void)out_size; (void)ws_size;
  const float* x_q = (const float*)d_in[0];
  const float* x_c = (const float*)d_in[1];
  const int*   src_q = (const int*)d_in[2];
  const int*   dst_q = (const int*)d_in[3];
  const int*   src_c = (const int*)d_in[4];
  const int*   dst_c = (const int*)d_in[5];
  const float* Wg0 = (const float*)d_in[6];
  const float* bg0 = (const float*)d_in[7];
  const float* Wg1 = (const float*)d_in[8];
  const float* bg1 = (const float*)d_in[9];
  const float* Wg2 = (const float*)d_in[10];
  const float* bg2 = (const float*)d_in[11];
  const float* cw0 = (const float*)d_in[12];
  const float* cb0 = (const float*)d_in[13];
  const float* cw1 = (const float*)d_in[14];
  const float* cb1 = (const float*)d_in[15];
  const float* Wl0 = (const float*)d_in[16];
  const float* bl0 = (const float*)d_in[17];
  const float* Wl1 = (const float*)d_in[18];
  const float* bl1 = (const float*)d_in[19];
  const float* Wsc = (const float*)d_in[20];
  const float* bsc = (const float*)d_in[21];
  float* out = (float*)d_out;

  float* ws = (float*)d_ws;
  float* qf0 = ws; ws += (size_t)NB * MM * 64;
  float* qf1 = ws; ws += (size_t)NB * MM * 32;
  float* qf2 = ws; ws += (size_t)NB * MM * 16;
  float* cf0 = ws; ws += (size_t)NB * MM * 64;
  float* cf1 = ws; ws += (size_t)NB * MM * 32;
  float* cf2 = ws; ws += (size_t)NB * MM * 16;
  float* sim = ws; ws += (size_t)NB * 64 * 64;
  float* p1  = ws; ws += (size_t)NB * 8 * 32 * 32;
  float* hcat = ws; ws += (size_t)NB * 48 * 16 * 16;
  float* l0  = ws; ws += (size_t)NB * 256;
  // total ~20.1M floats (~80 MB) of d_ws

  gcn_kernel<<<dim3(NB, 2), 256, 0, stream>>>(x_q, x_c, src_q, dst_q, src_c, dst_c,
      Wg0, bg0, Wg1, bg1, Wg2, bg2, qf0, qf1, qf2, cf0, cf1, cf2);

  for (int i = 0; i < 3; ++i) {
    if (i == 0) sim_kernel<64><<<NB, 256, 0, stream>>>(qf0, cf0, sim);
    if (i == 1) sim_kernel<32><<<NB, 256, 0, stream>>>(qf1, cf1, sim);
    if (i == 2) sim_kernel<16><<<NB, 256, 0, stream>>>(qf2, cf2, sim);
    conv1_kernel<<<NB, 256, 0, stream>>>(sim, cw0, cb0, i, p1);
    conv2_kernel<<<NB, 256, 0, stream>>>(p1, cw1, cb1, i, hcat);
  }

  init_l0<<<NB, 256, 0, stream>>>(bl0, l0);
  lin0_kernel<<<dim3(8, 4, 8), 256, 0, stream>>>(hcat, Wl0, l0);
  head_kernel<<<NB, 64, 0, stream>>>(l0, Wl1, bl1, Wsc, bsc, out);
}

// Round 2
// 371.975 us; speedup vs baseline: 2.0601x; 2.0601x over previous
//
#include <hip/hip_runtime.h>
#include <math.h>

#define NB 512      // graph pairs
#define MM 64       // nodes per graph
#define EPGc 512    // edges per graph

// acc[j] += sum_kk a[kk] * b_kk[j]
__device__ __forceinline__ void fma4x4(float (&acc)[4], const float4 a,
    const float4 b0, const float4 b1, const float4 b2, const float4 b3)
{
  acc[0] = fmaf(a.x, b0.x, acc[0]); acc[0] = fmaf(a.y, b1.x, acc[0]);
  acc[0] = fmaf(a.z, b2.x, acc[0]); acc[0] = fmaf(a.w, b3.x, acc[0]);
  acc[1] = fmaf(a.x, b0.y, acc[1]); acc[1] = fmaf(a.y, b1.y, acc[1]);
  acc[1] = fmaf(a.z, b2.y, acc[1]); acc[1] = fmaf(a.w, b3.y, acc[1]);
  acc[2] = fmaf(a.x, b0.z, acc[2]); acc[2] = fmaf(a.y, b1.z, acc[2]);
  acc[2] = fmaf(a.z, b2.z, acc[2]); acc[2] = fmaf(a.w, b3.z, acc[2]);
  acc[3] = fmaf(a.x, b0.w, acc[3]); acc[3] = fmaf(a.y, b1.w, acc[3]);
  acc[3] = fmaf(a.z, b2.w, acc[3]); acc[3] = fmaf(a.w, b3.w, acc[3]);
}

// ----------------------------- GCN: dense-adjacency, register-tiled LDS GEMMs -----------------------------
// sA: 64x64 stride 68.  sh: node feats, stride Fin+4 in / Fout+4 out.  st: h@W, stride Fout.
template<int Fin, int Fout, bool RELU>
__device__ __forceinline__ void gcn_layer(
    const float* __restrict__ W, const float* __restrict__ bias,
    const float* sA, float* sh, float* st, float* sW,
    float* __restrict__ outG, int g, int tid)
{
  constexpr int SIN = Fin + 4;
  constexpr int SOUT = Fout + 4;
  constexpr int TPR = Fout / 4;                      // f-tiles per node row
  constexpr int TR  = (Fout == 64) ? 4 : (Fout == 32 ? 2 : 1);
  const int n0 = (tid / TPR) * TR;
  const int f0 = (tid % TPR) * 4;

  for (int i = tid; i < Fin * Fout / 4; i += 256)
    *reinterpret_cast<float4*>(sW + i * 4) = *reinterpret_cast<const float4*>(W + i * 4);
  __syncthreads();

  // st = sh @ W   (64 x Fout)
  {
    float acc[TR][4];
#pragma unroll
    for (int i = 0; i < TR; ++i) { acc[i][0] = 0; acc[i][1] = 0; acc[i][2] = 0; acc[i][3] = 0; }
#pragma unroll
    for (int k = 0; k < Fin; k += 4) {
      float4 b0 = *reinterpret_cast<const float4*>(sW + (k + 0) * Fout + f0);
      float4 b1 = *reinterpret_cast<const float4*>(sW + (k + 1) * Fout + f0);
      float4 b2 = *reinterpret_cast<const float4*>(sW + (k + 2) * Fout + f0);
      float4 b3 = *reinterpret_cast<const float4*>(sW + (k + 3) * Fout + f0);
#pragma unroll
      for (int i = 0; i < TR; ++i) {
        float4 a = *reinterpret_cast<const float4*>(sh + (n0 + i) * SIN + k);
        fma4x4(acc[i], a, b0, b1, b2, b3);
      }
    }
#pragma unroll
    for (int i = 0; i < TR; ++i)
      *reinterpret_cast<float4*>(st + (n0 + i) * Fout + f0) =
          make_float4(acc[i][0], acc[i][1], acc[i][2], acc[i][3]);
  }
  __syncthreads();

  // out = A_hat @ st + bias ; write global pre-relu feats; relu into sh (stride SOUT)
  {
    float acc[TR][4];
#pragma unroll
    for (int i = 0; i < TR; ++i) { acc[i][0] = 0; acc[i][1] = 0; acc[i][2] = 0; acc[i][3] = 0; }
#pragma unroll
    for (int k = 0; k < 64; k += 4) {
      float4 b0 = *reinterpret_cast<const float4*>(st + (k + 0) * Fout + f0);
      float4 b1 = *reinterpret_cast<const float4*>(st + (k + 1) * Fout + f0);
      float4 b2 = *reinterpret_cast<const float4*>(st + (k + 2) * Fout + f0);
      float4 b3 = *reinterpret_cast<const float4*>(st + (k + 3) * Fout + f0);
#pragma unroll
      for (int i = 0; i < TR; ++i) {
        float4 a = *reinterpret_cast<const float4*>(sA + (n0 + i) * 68 + k);
        fma4x4(acc[i], a, b0, b1, b2, b3);
      }
    }
    float4 bv = *reinterpret_cast<const float4*>(bias + f0);
#pragma unroll
    for (int i = 0; i < TR; ++i) {
      float4 v = make_float4(acc[i][0] + bv.x, acc[i][1] + bv.y,
                             acc[i][2] + bv.z, acc[i][3] + bv.w);
      *reinterpret_cast<float4*>(outG + ((size_t)(g * MM + n0 + i) * Fout) + f0) = v;
      float4 r = RELU ? make_float4(fmaxf(v.x, 0.f), fmaxf(v.y, 0.f),
                                    fmaxf(v.z, 0.f), fmaxf(v.w, 0.f)) : v;
      *reinterpret_cast<float4*>(sh + (n0 + i) * SOUT + f0) = r;
    }
  }
  __syncthreads();
}

__global__ __launch_bounds__(256) void gcn_kernel(
    const float* __restrict__ xq, const float* __restrict__ xc,
    const int* __restrict__ srcq, const int* __restrict__ dstq,
    const int* __restrict__ srcc, const int* __restrict__ dstc,
    const float* __restrict__ Wg0, const float* __restrict__ bg0,
    const float* __restrict__ Wg1, const float* __restrict__ bg1,
    const float* __restrict__ Wg2, const float* __restrict__ bg2,
    float* __restrict__ qf0, float* __restrict__ qf1, float* __restrict__ qf2,
    float* __restrict__ cf0, float* __restrict__ cf1, float* __restrict__ cf2)
{
  __shared__ __align__(16) float sA[64 * 68];
  __shared__ __align__(16) float sh[64 * 68];
  __shared__ __align__(16) float st[64 * 64];
  __shared__ __align__(16) float sW[2048];
  __shared__ float sDinv[MM];
  __shared__ int sDeg[MM];

  const int g = blockIdx.x;
  const int which = blockIdx.y;
  const float* x = which ? xc : xq;
  const int* src = which ? srcc : srcq;
  const int* dst = which ? dstc : dstq;
  float* f0p = which ? cf0 : qf0;
  float* f1p = which ? cf1 : qf1;
  float* f2p = which ? cf2 : qf2;
  const int tid = threadIdx.x;

  for (int i = tid; i < 64 * 68; i += 256) sA[i] = 0.f;
  if (tid < MM) sDeg[tid] = 1;   // self loop
  __syncthreads();
  for (int e = tid; e < EPGc; e += 256)
    atomicAdd(&sDeg[dst[g * EPGc + e] - g * MM], 1);
  __syncthreads();
  if (tid < MM) sDinv[tid] = rsqrtf((float)sDeg[tid]);
  __syncthreads();
  for (int e = tid; e < EPGc; e += 256) {
    int s = src[g * EPGc + e] - g * MM;
    int d = dst[g * EPGc + e] - g * MM;
    atomicAdd(&sA[d * 68 + s], sDinv[s] * sDinv[d]);
  }
  if (tid < MM) atomicAdd(&sA[tid * 68 + tid], sDinv[tid] * sDinv[tid]);
  // load x (64 x 32) into sh stride 36
  for (int i = tid; i < 512; i += 256) {
    float4 v = *reinterpret_cast<const float4*>(x + (size_t)g * 2048 + i * 4);
    int n = (i * 4) >> 5, k = (i * 4) & 31;
    *reinterpret_cast<float4*>(sh + n * 36 + k) = v;
  }
  __syncthreads();

  gcn_layer<32, 64, true >(Wg0, bg0, sA, sh, st, sW, f0p, g, tid);
  gcn_layer<64, 32, true >(Wg1, bg1, sA, sh, st, sW, f1p, g, tid);
  gcn_layer<32, 16, false>(Wg2, bg2, sA, sh, st, sW, f2p, g, tid);
}

// ----------------------------- fused sim + conv1 + conv2 (per graph, per sim-matrix) -----------------------------
template<int F>
__device__ __forceinline__ void sim_compute(const float* __restrict__ qf,
    const float* __restrict__ cf, float* sq, float* scT, float* ssim, int g, int tid)
{
  for (int i = tid; i < 64 * F / 4; i += 256) {
    float4 v = *reinterpret_cast<const float4*>(qf + (size_t)g * 64 * F + i * 4);
    int n = (i * 4) / F, f = (i * 4) % F;
    *reinterpret_cast<float4*>(sq + n * 68 + f) = v;
  }
  for (int i = tid; i < 64 * F / 4; i += 256) {
    float4 v = *reinterpret_cast<const float4*>(cf + (size_t)g * 64 * F + i * 4);
    int n = (i * 4) / F, f = (i * 4) % F;
    scT[(f + 0) * 68 + n] = v.x; scT[(f + 1) * 68 + n] = v.y;
    scT[(f + 2) * 68 + n] = v.z; scT[(f + 3) * 68 + n] = v.w;
  }
  for (int i = tid; i < 68 * 68; i += 256) ssim[i] = 0.f;
  __syncthreads();

  const int tm = (tid >> 4) << 2;
  const int tn = (tid & 15) << 2;
  float acc[4][4];
#pragma unroll
  for (int i = 0; i < 4; ++i) { acc[i][0] = 0; acc[i][1] = 0; acc[i][2] = 0; acc[i][3] = 0; }
#pragma unroll
  for (int k = 0; k < F; k += 4) {
    float4 c0 = *reinterpret_cast<const float4*>(scT + (k + 0) * 68 + tn);
    float4 c1 = *reinterpret_cast<const float4*>(scT + (k + 1) * 68 + tn);
    float4 c2 = *reinterpret_cast<const float4*>(scT + (k + 2) * 68 + tn);
    float4 c3 = *reinterpret_cast<const float4*>(scT + (k + 3) * 68 + tn);
#pragma unroll
    for (int i = 0; i < 4; ++i) {
      float4 a = *reinterpret_cast<const float4*>(sq + (tm + i) * 68 + k);
      fma4x4(acc[i], a, c0, c1, c2, c3);
    }
  }
#pragma unroll
  for (int i = 0; i < 4; ++i)
#pragma unroll
    for (int j = 0; j < 4; ++j)
      ssim[(tm + i + 2) * 68 + (tn + j + 2)] = acc[i][j];
  __syncthreads();
}

__device__ __forceinline__ void conv1_compute(const float* ssim, float* p1,
    const float* __restrict__ w, const float* __restrict__ bb, int tid)
{
  for (int it = 0; it < 4; ++it) {
    int pos = tid + (it << 8);           // 32x32 pooled grid
    int y = pos >> 5, x = pos & 31;
    float win[6][6];
#pragma unroll
    for (int u = 0; u < 6; ++u)
#pragma unroll
      for (int v = 0; v < 6; ++v) win[u][v] = ssim[(2 * y + u) * 68 + (2 * x + v)];
    float acc[8][4];
#pragma unroll
    for (int c = 0; c < 8; ++c) { acc[c][0] = 0; acc[c][1] = 0; acc[c][2] = 0; acc[c][3] = 0; }
#pragma unroll
    for (int u = 0; u < 5; ++u)
#pragma unroll
      for (int v = 0; v < 5; ++v) {
#pragma unroll
        for (int c = 0; c < 8; ++c) {
          float wt = w[c * 25 + u * 5 + v];
          acc[c][0] = fmaf(win[u][v],         wt, acc[c][0]);
          acc[c][1] = fmaf(win[u][v + 1],     wt, acc[c][1]);
          acc[c][2] = fmaf(win[u + 1][v],     wt, acc[c][2]);
          acc[c][3] = fmaf(win[u + 1][v + 1], wt, acc[c][3]);
        }
      }
#pragma unroll
    for (int c = 0; c < 8; ++c) {
      float mx = fmaxf(fmaxf(acc[c][0], acc[c][1]), fmaxf(acc[c][2], acc[c][3])) + bb[c];
      p1[c * 1056 + y * 33 + x] = fmaxf(mx, 0.f);   // stride-33 rows: kills 4-way conflicts
    }
  }
  __syncthreads();
}

__device__ __forceinline__ void conv2_compute(const float* p1,
    const float* __restrict__ w, const float* __restrict__ bb,
    float* __restrict__ hcat, int g, int lvl, int tid)
{
  const int ty = tid >> 4, tx = tid & 15;   // pooled 16x16
  float acc[16][4];
#pragma unroll
  for (int c = 0; c < 16; ++c) { acc[c][0] = 0; acc[c][1] = 0; acc[c][2] = 0; acc[c][3] = 0; }

  for (int ic = 0; ic < 8; ++ic) {
    float win[6][6];
#pragma unroll
    for (int u = 0; u < 6; ++u) {
      int r = 2 * ty + u - 2;
      bool rv = (r >= 0) && (r < 32);
#pragma unroll
      for (int v = 0; v < 6; ++v) {
        int cc = 2 * tx + v - 2;
        bool cv = (cc >= 0) && (cc < 32);
        win[u][v] = (rv && cv) ? p1[ic * 1056 + r * 33 + cc] : 0.f;
      }
    }
#pragma unroll
    for (int u = 0; u < 5; ++u)
#pragma unroll
      for (int v = 0; v < 5; ++v) {
#pragma unroll
        for (int c = 0; c < 16; ++c) {
          float wt = w[(c * 8 + ic) * 25 + u * 5 + v];
          acc[c][0] = fmaf(win[u][v],         wt, acc[c][0]);
          acc[c][1] = fmaf(win[u][v + 1],     wt, acc[c][1]);
          acc[c][2] = fmaf(win[u + 1][v],     wt, acc[c][2]);
          acc[c][3] = fmaf(win[u + 1][v + 1], wt, acc[c][3]);
        }
      }
  }
#pragma unroll
  for (int c = 0; c < 16; ++c) {
    float mx = fmaxf(fmaxf(acc[c][0], acc[c][1]), fmaxf(acc[c][2], acc[c][3])) + bb[c];
    hcat[((size_t)g * 48 + lvl * 16 + c) * 256 + tid] = fmaxf(mx, 0.f);
  }
}

__global__ __launch_bounds__(256) void simconv_kernel(
    const float* __restrict__ qf0, const float* __restrict__ qf1, const float* __restrict__ qf2,
    const float* __restrict__ cf0, const float* __restrict__ cf1, const float* __restrict__ cf2,
    const float* __restrict__ cw0, const float* __restrict__ cb0,
    const float* __restrict__ cw1, const float* __restrict__ cb1,
    float* __restrict__ hcat)
{
  __shared__ __align__(16) float smem[13328];   // 53312 B -> 3 blocks/CU
  float* sq   = smem;            // 64*68 = 4352
  float* scT  = smem + 4352;     // 64*68 = 4352 (transposed cf)
  float* ssim = smem + 8704;     // 68*68 = 4624 (padded sim, halo 2)
  float* p1   = smem;            // 8*1056 = 8448, aliases sq/scT after sim

  const int g = blockIdx.x, lvl = blockIdx.y, tid = threadIdx.x;

  if (lvl == 0)      sim_compute<64>(qf0, cf0, sq, scT, ssim, g, tid);
  else if (lvl == 1) sim_compute<32>(qf1, cf1, sq, scT, ssim, g, tid);
  else               sim_compute<16>(qf2, cf2, sq, scT, ssim, g, tid);

  conv1_compute(ssim, p1, cw0 + lvl * 200, cb0 + lvl * 8, tid);
  conv2_compute(p1, cw1 + lvl * 3200, cb1 + lvl * 16, hcat, g, lvl, tid);
}

// ----------------------------- linear 0: (512,12288)@(12288,256), split-K, atomic accumulate -----------------------------
__global__ __launch_bounds__(256) void init_l0(const float* __restrict__ bl0, float* __restrict__ l0)
{
  int i = blockIdx.x * 256 + threadIdx.x;
  l0[i] = bl0[i & 255];
}

__global__ __launch_bounds__(256) void lin0_kernel(
    const float* __restrict__ A, const float* __restrict__ Wl0, float* __restrict__ l0)
{
  __shared__ float sA[64][17];
  __shared__ float sB[16][65];
  const int rb = blockIdx.x * 64;
  const int cb = blockIdx.y * 64;
  const int k0 = blockIdx.z * 1536;
  const int tid = threadIdx.x;
  const int tx = tid & 15, ty = tid >> 4;
  float acc[4][4] = {};

  for (int kt = 0; kt < 1536; kt += 16) {
    {
      int r = (tid >> 4), k = tid & 15;
#pragma unroll
      for (int p = 0; p < 4; ++p)
        sA[r + p * 16][k] = A[(size_t)(rb + r + p * 16) * 12288 + k0 + kt + k];
    }
    {
      int kk = (tid >> 6), c = tid & 63;
#pragma unroll
      for (int p = 0; p < 4; ++p)
        sB[kk + p * 4][c] = Wl0[(size_t)(k0 + kt + kk + p * 4) * 256 + cb + c];
    }
    __syncthreads();
#pragma unroll
    for (int k = 0; k < 16; ++k) {
      float a[4], b[4];
#pragma unroll
      for (int i = 0; i < 4; ++i) a[i] = sA[ty * 4 + i][k];
#pragma unroll
      for (int j = 0; j < 4; ++j) b[j] = sB[k][tx * 4 + j];
#pragma unroll
      for (int i = 0; i < 4; ++i)
#pragma unroll
        for (int j = 0; j < 4; ++j) acc[i][j] = fmaf(a[i], b[j], acc[i][j]);
    }
    __syncthreads();
  }
#pragma unroll
  for (int i = 0; i < 4; ++i)
#pragma unroll
    for (int j = 0; j < 4; ++j)
      atomicAdd(&l0[(size_t)(rb + ty * 4 + i) * 256 + cb + tx * 4 + j], acc[i][j]);
}

// ----------------------------- head -----------------------------
__global__ __launch_bounds__(64) void head_kernel(
    const float* __restrict__ l0, const float* __restrict__ Wl1, const float* __restrict__ bl1,
    const float* __restrict__ Wsc, const float* __restrict__ bsc, float* __restrict__ out)
{
  __shared__ float sr[256];
  const int b = blockIdx.x, j = threadIdx.x;
  for (int k = j; k < 256; k += 64) sr[k] = fmaxf(l0[(size_t)b * 256 + k], 0.f);
  __syncthreads();
  float acc = bl1[j];
  for (int k = 0; k < 256; ++k) acc = fmaf(sr[k], Wl1[k * 64 + j], acc);
  float v = fmaxf(acc, 0.f) * Wsc[j];
#pragma unroll
  for (int off = 32; off > 0; off >>= 1) v += __shfl_down(v, off);
  if (j == 0) out[b] = 1.f / (1.f + expf(-(v + bsc[0])));
}

// ----------------------------- launch -----------------------------
extern "C" void kernel_launch(void* const* d_in, const int* in_sizes, int n_in,
                              void* d_out, int out_size, void* d_ws, size_t ws_size,
                              hipStream_t stream)
{
  (void)in_sizes; (void)n_in; (void)out_size; (void)ws_size;
  const float* x_q = (const float*)d_in[0];
  const float* x_c = (const float*)d_in[1];
  const int*   src_q = (const int*)d_in[2];
  const int*   dst_q = (const int*)d_in[3];
  const int*   src_c = (const int*)d_in[4];
  const int*   dst_c = (const int*)d_in[5];
  const float* Wg0 = (const float*)d_in[6];
  const float* bg0 = (const float*)d_in[7];
  const float* Wg1 = (const float*)d_in[8];
  const float* bg1 = (const float*)d_in[9];
  const float* Wg2 = (const float*)d_in[10];
  const float* bg2 = (const float*)d_in[11];
  const float* cw0 = (const float*)d_in[12];
  const float* cb0 = (const float*)d_in[13];
  const float* cw1 = (const float*)d_in[14];
  const float* cb1 = (const float*)d_in[15];
  const float* Wl0 = (const float*)d_in[16];
  const float* bl0 = (const float*)d_in[17];
  const float* Wl1 = (const float*)d_in[18];
  const float* bl1 = (const float*)d_in[19];
  const float* Wsc = (const float*)d_in[20];
  const float* bsc = (const float*)d_in[21];
  float* out = (float*)d_out;

  float* ws = (float*)d_ws;
  float* qf0 = ws; ws += (size_t)NB * MM * 64;
  float* qf1 = ws; ws += (size_t)NB * MM * 32;
  float* qf2 = ws; ws += (size_t)NB * MM * 16;
  float* cf0 = ws; ws += (size_t)NB * MM * 64;
  float* cf1 = ws; ws += (size_t)NB * MM * 32;
  float* cf2 = ws; ws += (size_t)NB * MM * 16;
  float* hcat = ws; ws += (size_t)NB * 48 * 256;
  float* l0  = ws; ws += (size_t)NB * 256;
  // ~13.6M floats (~54 MB) of d_ws

  gcn_kernel<<<dim3(NB, 2), 256, 0, stream>>>(x_q, x_c, src_q, dst_q, src_c, dst_c,
      Wg0, bg0, Wg1, bg1, Wg2, bg2, qf0, qf1, qf2, cf0, cf1, cf2);

  simconv_kernel<<<dim3(NB, 3), 256, 0, stream>>>(qf0, qf1, qf2, cf0, cf1, cf2,
      cw0, cb0, cw1, cb1, hcat);

  init_l0<<<NB, 256, 0, stream>>>(bl0, l0);
  lin0_kernel<<<dim3(8, 4, 8), 256, 0, stream>>>(hcat, Wl0, l0);
  head_kernel<<<NB, 64, 0, stream>>>(l0, Wl1, bl1, Wsc, bsc, out);
}

// Round 4
// 285.330 us; speedup vs baseline: 2.6857x; 1.3037x over previous
//
#include <hip/hip_runtime.h>
#include <math.h>

#define NB 512      // graph pairs
#define MM 64       // nodes per graph
#define EPGc 512    // edges per graph

typedef __attribute__((ext_vector_type(8))) short s16x8;
typedef __attribute__((ext_vector_type(4))) float f32x4;

__device__ __forceinline__ unsigned short f2bf(float f) {
  union { float f; unsigned int u; } c; c.f = f;
  unsigned int u = c.u;
  return (unsigned short)((u + 0x7FFFu + ((u >> 16) & 1u)) >> 16);   // RNE
}
__device__ __forceinline__ float bf2f(unsigned short h) {
  union { unsigned int u; float f; } c; c.u = ((unsigned int)h) << 16;
  return c.f;
}

// acc[j] += sum_kk a[kk] * b_kk[j]
__device__ __forceinline__ void fma4x4(float (&acc)[4], const float4 a,
    const float4 b0, const float4 b1, const float4 b2, const float4 b3)
{
  acc[0] = fmaf(a.x, b0.x, acc[0]); acc[0] = fmaf(a.y, b1.x, acc[0]);
  acc[0] = fmaf(a.z, b2.x, acc[0]); acc[0] = fmaf(a.w, b3.x, acc[0]);
  acc[1] = fmaf(a.x, b0.y, acc[1]); acc[1] = fmaf(a.y, b1.y, acc[1]);
  acc[1] = fmaf(a.z, b2.y, acc[1]); acc[1] = fmaf(a.w, b3.y, acc[1]);
  acc[2] = fmaf(a.x, b0.z, acc[2]); acc[2] = fmaf(a.y, b1.z, acc[2]);
  acc[2] = fmaf(a.z, b2.z, acc[2]); acc[2] = fmaf(a.w, b3.z, acc[2]);
  acc[3] = fmaf(a.x, b0.w, acc[3]); acc[3] = fmaf(a.y, b1.w, acc[3]);
  acc[3] = fmaf(a.z, b2.w, acc[3]); acc[3] = fmaf(a.w, b3.w, acc[3]);
}

// ----------------------------- GCN: dense-adjacency, register-tiled LDS GEMMs -----------------------------
template<int Fin, int Fout, bool RELU>
__device__ __forceinline__ void gcn_layer(
    const float* __restrict__ W, const float* __restrict__ bias,
    const float* sA, float* sh, float* st, float* sW,
    float* __restrict__ outG, int g, int tid)
{
  constexpr int SIN = Fin + 4;
  constexpr int SOUT = Fout + 4;
  constexpr int TPR = Fout / 4;
  constexpr int TR  = (Fout == 64) ? 4 : (Fout == 32 ? 2 : 1);
  const int n0 = (tid / TPR) * TR;
  const int f0 = (tid % TPR) * 4;

  for (int i = tid; i < Fin * Fout / 4; i += 256)
    *reinterpret_cast<float4*>(sW + i * 4) = *reinterpret_cast<const float4*>(W + i * 4);
  __syncthreads();

  {
    float acc[TR][4];
#pragma unroll
    for (int i = 0; i < TR; ++i) { acc[i][0] = 0; acc[i][1] = 0; acc[i][2] = 0; acc[i][3] = 0; }
#pragma unroll
    for (int k = 0; k < Fin; k += 4) {
      float4 b0 = *reinterpret_cast<const float4*>(sW + (k + 0) * Fout + f0);
      float4 b1 = *reinterpret_cast<const float4*>(sW + (k + 1) * Fout + f0);
      float4 b2 = *reinterpret_cast<const float4*>(sW + (k + 2) * Fout + f0);
      float4 b3 = *reinterpret_cast<const float4*>(sW + (k + 3) * Fout + f0);
#pragma unroll
      for (int i = 0; i < TR; ++i) {
        float4 a = *reinterpret_cast<const float4*>(sh + (n0 + i) * SIN + k);
        fma4x4(acc[i], a, b0, b1, b2, b3);
      }
    }
#pragma unroll
    for (int i = 0; i < TR; ++i)
      *reinterpret_cast<float4*>(st + (n0 + i) * Fout + f0) =
          make_float4(acc[i][0], acc[i][1], acc[i][2], acc[i][3]);
  }
  __syncthreads();

  {
    float acc[TR][4];
#pragma unroll
    for (int i = 0; i < TR; ++i) { acc[i][0] = 0; acc[i][1] = 0; acc[i][2] = 0; acc[i][3] = 0; }
#pragma unroll
    for (int k = 0; k < 64; k += 4) {
      float4 b0 = *reinterpret_cast<const float4*>(st + (k + 0) * Fout + f0);
      float4 b1 = *reinterpret_cast<const float4*>(st + (k + 1) * Fout + f0);
      float4 b2 = *reinterpret_cast<const float4*>(st + (k + 2) * Fout + f0);
      float4 b3 = *reinterpret_cast<const float4*>(st + (k + 3) * Fout + f0);
#pragma unroll
      for (int i = 0; i < TR; ++i) {
        float4 a = *reinterpret_cast<const float4*>(sA + (n0 + i) * 68 + k);
        fma4x4(acc[i], a, b0, b1, b2, b3);
      }
    }
    float4 bv = *reinterpret_cast<const float4*>(bias + f0);
#pragma unroll
    for (int i = 0; i < TR; ++i) {
      float4 v = make_float4(acc[i][0] + bv.x, acc[i][1] + bv.y,
                             acc[i][2] + bv.z, acc[i][3] + bv.w);
      *reinterpret_cast<float4*>(outG + ((size_t)(g * MM + n0 + i) * Fout) + f0) = v;
      float4 r = RELU ? make_float4(fmaxf(v.x, 0.f), fmaxf(v.y, 0.f),
                                    fmaxf(v.z, 0.f), fmaxf(v.w, 0.f)) : v;
      *reinterpret_cast<float4*>(sh + (n0 + i) * SOUT + f0) = r;
    }
  }
  __syncthreads();
}

__global__ __launch_bounds__(256) void gcn_kernel(
    const float* __restrict__ xq, const float* __restrict__ xc,
    const int* __restrict__ srcq, const int* __restrict__ dstq,
    const int* __restrict__ srcc, const int* __restrict__ dstc,
    const float* __restrict__ Wg0, const float* __restrict__ bg0,
    const float* __restrict__ Wg1, const float* __restrict__ bg1,
    const float* __restrict__ Wg2, const float* __restrict__ bg2,
    float* __restrict__ qf0, float* __restrict__ qf1, float* __restrict__ qf2,
    float* __restrict__ cf0, float* __restrict__ cf1, float* __restrict__ cf2)
{
  __shared__ __align__(16) float sA[64 * 68];
  __shared__ __align__(16) float sh[64 * 68];
  __shared__ __align__(16) float st[64 * 64];
  __shared__ __align__(16) float sW[2048];
  __shared__ float sDinv[MM];
  __shared__ int sDeg[MM];

  const int g = blockIdx.x;
  const int which = blockIdx.y;
  const float* x = which ? xc : xq;
  const int* src = which ? srcc : srcq;
  const int* dst = which ? dstc : dstq;
  float* f0p = which ? cf0 : qf0;
  float* f1p = which ? cf1 : qf1;
  float* f2p = which ? cf2 : qf2;
  const int tid = threadIdx.x;

  for (int i = tid; i < 64 * 68; i += 256) sA[i] = 0.f;
  if (tid < MM) sDeg[tid] = 1;
  __syncthreads();
  for (int e = tid; e < EPGc; e += 256)
    atomicAdd(&sDeg[dst[g * EPGc + e] - g * MM], 1);
  __syncthreads();
  if (tid < MM) sDinv[tid] = rsqrtf((float)sDeg[tid]);
  __syncthreads();
  for (int e = tid; e < EPGc; e += 256) {
    int s = src[g * EPGc + e] - g * MM;
    int d = dst[g * EPGc + e] - g * MM;
    atomicAdd(&sA[d * 68 + s], sDinv[s] * sDinv[d]);
  }
  if (tid < MM) atomicAdd(&sA[tid * 68 + tid], sDinv[tid] * sDinv[tid]);
  for (int i = tid; i < 512; i += 256) {
    float4 v = *reinterpret_cast<const float4*>(x + (size_t)g * 2048 + i * 4);
    int n = (i * 4) >> 5, k = (i * 4) & 31;
    *reinterpret_cast<float4*>(sh + n * 36 + k) = v;
  }
  __syncthreads();

  gcn_layer<32, 64, true >(Wg0, bg0, sA, sh, st, sW, f0p, g, tid);
  gcn_layer<64, 32, true >(Wg1, bg1, sA, sh, st, sW, f1p, g, tid);
  gcn_layer<32, 16, false>(Wg2, bg2, sA, sh, st, sW, f2p, g, tid);
}

// ----------------------------- conv2 weight prepack: A-fragment layout per lane -----------------------------
// packA[((lvl*7+g)*64 + lane)*8 + j] = W[oc=lane&15][k=g*32 + (lane>>4)*8 + j], k=(shift s, ic j), s=g*4+(lane>>4)
__global__ __launch_bounds__(256) void pack_w(const float* __restrict__ cw1,
                                              unsigned short* __restrict__ packA)
{
  int i = blockIdx.x * 256 + threadIdx.x;
  if (i >= 3 * 7 * 64 * 8) return;
  int j = i & 7, l = (i >> 3) & 63, g = (i >> 9) % 7, lvl = i / 3584;
  int oc = l & 15, sg = l >> 4;
  int s = g * 4 + sg;
  float v = 0.f;
  if (s < 25) v = cw1[((size_t)(lvl * 16 + oc) * 8 + j) * 25 + s];
  packA[i] = f2bf(v);
}

// ----------------------------- fused sim + conv1 + conv2(MFMA) + pool -----------------------------
template<int F>
__device__ __forceinline__ void sim_compute(const float* __restrict__ qf,
    const float* __restrict__ cf, float* sq, float* scT, float* ssim, int g, int tid)
{
  for (int i = tid; i < 64 * F / 4; i += 256) {
    float4 v = *reinterpret_cast<const float4*>(qf + (size_t)g * 64 * F + i * 4);
    int n = (i * 4) / F, f = (i * 4) % F;
    *reinterpret_cast<float4*>(sq + n * 68 + f) = v;
  }
  for (int i = tid; i < 64 * F / 4; i += 256) {
    float4 v = *reinterpret_cast<const float4*>(cf + (size_t)g * 64 * F + i * 4);
    int n = (i * 4) / F, f = (i * 4) % F;
    scT[(f + 0) * 68 + n] = v.x; scT[(f + 1) * 68 + n] = v.y;
    scT[(f + 2) * 68 + n] = v.z; scT[(f + 3) * 68 + n] = v.w;
  }
  for (int i = tid; i < 68 * 68; i += 256) ssim[i] = 0.f;
  __syncthreads();

  const int tm = (tid >> 4) << 2;
  const int tn = (tid & 15) << 2;
  float acc[4][4];
#pragma unroll
  for (int i = 0; i < 4; ++i) { acc[i][0] = 0; acc[i][1] = 0; acc[i][2] = 0; acc[i][3] = 0; }
#pragma unroll
  for (int k = 0; k < F; k += 4) {
    float4 c0 = *reinterpret_cast<const float4*>(scT + (k + 0) * 68 + tn);
    float4 c1 = *reinterpret_cast<const float4*>(scT + (k + 1) * 68 + tn);
    float4 c2 = *reinterpret_cast<const float4*>(scT + (k + 2) * 68 + tn);
    float4 c3 = *reinterpret_cast<const float4*>(scT + (k + 3) * 68 + tn);
#pragma unroll
    for (int i = 0; i < 4; ++i) {
      float4 a = *reinterpret_cast<const float4*>(sq + (tm + i) * 68 + k);
      fma4x4(acc[i], a, c0, c1, c2, c3);
    }
  }
#pragma unroll
  for (int i = 0; i < 4; ++i)
#pragma unroll
    for (int j = 0; j < 4; ++j)
      ssim[(tm + i + 2) * 68 + (tn + j + 2)] = acc[i][j];
  __syncthreads();
}

// conv1 (fp32 VALU) -> pool -> bias -> relu -> bf16 channel-interleaved p1ci[36][36][8]
__device__ __forceinline__ void conv1_compute(const float* ssim, unsigned short* p1u,
    const float* __restrict__ w, const float* __restrict__ bb, int tid)
{
  // zero the halo frame: 272 cells > 256 threads -> MUST stride (R3 bug: `if (tid<272)`
  // left cells 256..271 = rows 30..33, cols {0,1,34,35} holding stale float bytes)
  for (int h = tid; h < 272; h += 256) {
    int r, c;
    if (h < 72)       { r = h / 36;             c = h % 36; }
    else if (h < 144) { r = 34 + (h - 72) / 36; c = (h - 72) % 36; }
    else { int z = h - 144; r = 2 + (z >> 2); int wq = z & 3; c = (wq < 2) ? wq : 32 + wq; }
    s16x8 zz = {0, 0, 0, 0, 0, 0, 0, 0};
    *reinterpret_cast<s16x8*>(p1u + (r * 36 + c) * 8) = zz;
  }

  for (int it = 0; it < 4; ++it) {
    int pos = tid + (it << 8);
    int y = pos >> 5, x = pos & 31;
    float win[6][6];
#pragma unroll
    for (int u = 0; u < 6; ++u)
#pragma unroll
      for (int v = 0; v < 6; ++v) win[u][v] = ssim[(2 * y + u) * 68 + (2 * x + v)];
    float acc[8][4];
#pragma unroll
    for (int c = 0; c < 8; ++c) { acc[c][0] = 0; acc[c][1] = 0; acc[c][2] = 0; acc[c][3] = 0; }
#pragma unroll
    for (int u = 0; u < 5; ++u)
#pragma unroll
      for (int v = 0; v < 5; ++v) {
#pragma unroll
        for (int c = 0; c < 8; ++c) {
          float wt = w[c * 25 + u * 5 + v];
          acc[c][0] = fmaf(win[u][v],         wt, acc[c][0]);
          acc[c][1] = fmaf(win[u][v + 1],     wt, acc[c][1]);
          acc[c][2] = fmaf(win[u + 1][v],     wt, acc[c][2]);
          acc[c][3] = fmaf(win[u + 1][v + 1], wt, acc[c][3]);
        }
      }
    s16x8 pk;
#pragma unroll
    for (int c = 0; c < 8; ++c) {
      float mx = fmaxf(fmaxf(acc[c][0], acc[c][1]), fmaxf(acc[c][2], acc[c][3])) + bb[c];
      pk[c] = (short)f2bf(fmaxf(mx, 0.f));
    }
    *reinterpret_cast<s16x8*>(p1u + ((y + 2) * 36 + (x + 2)) * 8) = pk;
  }
  __syncthreads();
}

__global__ __launch_bounds__(256) void simconv_kernel(
    const float* __restrict__ qf0, const float* __restrict__ qf1, const float* __restrict__ qf2,
    const float* __restrict__ cf0, const float* __restrict__ cf1, const float* __restrict__ cf2,
    const float* __restrict__ cw0, const float* __restrict__ cb0,
    const float* __restrict__ cb1, const unsigned short* __restrict__ packA,
    float* __restrict__ hcat)
{
  __shared__ __align__(16) float smem[13440];   // 53760 B -> 3 blocks/CU
  // phase layout (aliased, each handoff separated by __syncthreads):
  //   sim:   sq [0,4352)  scT [4352,8704)  ssim [8704,13328)
  //   conv1: reads ssim, writes p1ci = bf16 [36][36][8] at ushort(smem)[0..10368)
  //   conv2: reads p1ci, writes c2raw = bf16 [1024 pix][16 oc] at smem+5248 (32 KB)
  //   pool:  reads c2raw -> hcat
  float* sq   = smem;
  float* scT  = smem + 4352;
  float* ssim = smem + 8704;
  unsigned short* p1u = reinterpret_cast<unsigned short*>(smem);
  unsigned short* c2u = reinterpret_cast<unsigned short*>(smem + 5248);

  const int g = blockIdx.x, lvl = blockIdx.y, tid = threadIdx.x;

  if (lvl == 0)      sim_compute<64>(qf0, cf0, sq, scT, ssim, g, tid);
  else if (lvl == 1) sim_compute<32>(qf1, cf1, sq, scT, ssim, g, tid);
  else               sim_compute<16>(qf2, cf2, sq, scT, ssim, g, tid);

  conv1_compute(ssim, p1u, cw0 + lvl * 200, cb0 + lvl * 8, tid);
  // (conv1_compute ends with __syncthreads: p1ci complete, ssim dead)

  // ---- conv2 via MFMA: out[16 oc][1024 pix], K = 7 groups x 32 (shift s = gg*4+(l>>4), ic = j) ----
  {
    const int lane = tid & 63, wave = tid >> 6;
    const int col = lane & 15, q = lane >> 4;

    s16x8 afr[7];
#pragma unroll
    for (int gg = 0; gg < 7; ++gg)
      afr[gg] = *reinterpret_cast<const s16x8*>(packA + ((size_t)(lvl * 7 + gg) * 64 + lane) * 8);

    int off[7];
#pragma unroll
    for (int gg = 0; gg < 7; ++gg) {
      int s = gg * 4 + q; if (s > 24) s = 24;      // A is zero there; just read a valid addr
      off[gg] = (s / 5) * 288 + (s % 5) * 8;       // ushort units; row pitch 36*8
    }

    for (int tt = 0; tt < 16; ++tt) {
      int t = wave * 16 + tt;                       // n-tile: 16 pixels, row y=t>>1
      int base = (t >> 1) * 288 + (t & 1) * 128 + col * 8;
      f32x4 acc = {0.f, 0.f, 0.f, 0.f};
#pragma unroll
      for (int gg = 0; gg < 7; ++gg) {
        s16x8 b = *reinterpret_cast<const s16x8*>(p1u + base + off[gg]);
        acc = __builtin_amdgcn_mfma_f32_16x16x32_bf16(afr[gg], b, acc, 0, 0, 0);
      }
      int pix = t * 16 + col;
      unsigned short pk[4];
#pragma unroll
      for (int r = 0; r < 4; ++r) pk[r] = f2bf(acc[r]);   // oc = q*4 + r
      unsigned int w0 = (unsigned int)pk[0] | ((unsigned int)pk[1] << 16);
      unsigned int w1 = (unsigned int)pk[2] | ((unsigned int)pk[3] << 16);
      uint2 dw = make_uint2(w0, w1);
      *reinterpret_cast<uint2*>(c2u + pix * 16 + q * 4) = dw;   // ds_write_b64
    }
  }
  __syncthreads();

  // ---- pool 2x2 + bias + relu -> hcat ----
  {
    const float* bb = cb1 + lvl * 16;
#pragma unroll
    for (int m = 0; m < 4; ++m) {
      int u = m * 256 + tid;
      int q = u & 3, p = u >> 2;                    // p: pooled pixel, q: oc quarter
      int py = p >> 4, px = p & 15;
      float best[4] = {-1e30f, -1e30f, -1e30f, -1e30f};
#pragma unroll
      for (int dy = 0; dy < 2; ++dy)
#pragma unroll
        for (int dx = 0; dx < 2; ++dx) {
          uint2 dv = *reinterpret_cast<const uint2*>(
              c2u + (((2 * py + dy) * 32 + 2 * px + dx) * 16 + q * 4));
          best[0] = fmaxf(best[0], bf2f((unsigned short)(dv.x & 0xFFFF)));
          best[1] = fmaxf(best[1], bf2f((unsigned short)(dv.x >> 16)));
          best[2] = fmaxf(best[2], bf2f((unsigned short)(dv.y & 0xFFFF)));
          best[3] = fmaxf(best[3], bf2f((unsigned short)(dv.y >> 16)));
        }
#pragma unroll
      for (int r = 0; r < 4; ++r) {
        int oc = q * 4 + r;
        float val = fmaxf(best[r] + bb[oc], 0.f);
        hcat[((size_t)g * 48 + lvl * 16 + oc) * 256 + p] = val;
      }
    }
  }
}

// ----------------------------- linear 0: (512,12288)@(12288,256), split-K, atomic accumulate -----------------------------
__global__ __launch_bounds__(256) void init_l0(const float* __restrict__ bl0, float* __restrict__ l0)
{
  int i = blockIdx.x * 256 + threadIdx.x;
  l0[i] = bl0[i & 255];
}

__global__ __launch_bounds__(256) void lin0_kernel(
    const float* __restrict__ A, const float* __restrict__ Wl0, float* __restrict__ l0)
{
  __shared__ float sA[64][17];
  __shared__ float sB[16][65];
  const int rb = blockIdx.x * 64;
  const int cb = blockIdx.y * 64;
  const int k0 = blockIdx.z * 1536;
  const int tid = threadIdx.x;
  const int tx = tid & 15, ty = tid >> 4;
  float acc[4][4] = {};

  for (int kt = 0; kt < 1536; kt += 16) {
    {
      int r = (tid >> 4), k = tid & 15;
#pragma unroll
      for (int p = 0; p < 4; ++p)
        sA[r + p * 16][k] = A[(size_t)(rb + r + p * 16) * 12288 + k0 + kt + k];
    }
    {
      int kk = (tid >> 6), c = tid & 63;
#pragma unroll
      for (int p = 0; p < 4; ++p)
        sB[kk + p * 4][c] = Wl0[(size_t)(k0 + kt + kk + p * 4) * 256 + cb + c];
    }
    __syncthreads();
#pragma unroll
    for (int k = 0; k < 16; ++k) {
      float a[4], b[4];
#pragma unroll
      for (int i = 0; i < 4; ++i) a[i] = sA[ty * 4 + i][k];
#pragma unroll
      for (int j = 0; j < 4; ++j) b[j] = sB[k][tx * 4 + j];
#pragma unroll
      for (int i = 0; i < 4; ++i)
#pragma unroll
        for (int j = 0; j < 4; ++j) acc[i][j] = fmaf(a[i], b[j], acc[i][j]);
    }
    __syncthreads();
  }
#pragma unroll
  for (int i = 0; i < 4; ++i)
#pragma unroll
    for (int j = 0; j < 4; ++j)
      atomicAdd(&l0[(size_t)(rb + ty * 4 + i) * 256 + cb + tx * 4 + j], acc[i][j]);
}

// ----------------------------- head -----------------------------
__global__ __launch_bounds__(64) void head_kernel(
    const float* __restrict__ l0, const float* __restrict__ Wl1, const float* __restrict__ bl1,
    const float* __restrict__ Wsc, const float* __restrict__ bsc, float* __restrict__ out)
{
  __shared__ float sr[256];
  const int b = blockIdx.x, j = threadIdx.x;
  for (int k = j; k < 256; k += 64) sr[k] = fmaxf(l0[(size_t)b * 256 + k], 0.f);
  __syncthreads();
  float acc = bl1[j];
  for (int k = 0; k < 256; ++k) acc = fmaf(sr[k], Wl1[k * 64 + j], acc);
  float v = fmaxf(acc, 0.f) * Wsc[j];
#pragma unroll
  for (int off = 32; off > 0; off >>= 1) v += __shfl_down(v, off);
  if (j == 0) out[b] = 1.f / (1.f + expf(-(v + bsc[0])));
}

// ----------------------------- launch -----------------------------
extern "C" void kernel_launch(void* const* d_in, const int* in_sizes, int n_in,
                              void* d_out, int out_size, void* d_ws, size_t ws_size,
                              hipStream_t stream)
{
  (void)in_sizes; (void)n_in; (void)out_size; (void)ws_size;
  const float* x_q = (const float*)d_in[0];
  const float* x_c = (const float*)d_in[1];
  const int*   src_q = (const int*)d_in[2];
  const int*   dst_q = (const int*)d_in[3];
  const int*   src_c = (const int*)d_in[4];
  const int*   dst_c = (const int*)d_in[5];
  const float* Wg0 = (const float*)d_in[6];
  const float* bg0 = (const float*)d_in[7];
  const float* Wg1 = (const float*)d_in[8];
  const float* bg1 = (const float*)d_in[9];
  const float* Wg2 = (const float*)d_in[10];
  const float* bg2 = (const float*)d_in[11];
  const float* cw0 = (const float*)d_in[12];
  const float* cb0 = (const float*)d_in[13];
  const float* cw1 = (const float*)d_in[14];
  const float* cb1 = (const float*)d_in[15];
  const float* Wl0 = (const float*)d_in[16];
  const float* bl0 = (const float*)d_in[17];
  const float* Wl1 = (const float*)d_in[18];
  const float* bl1 = (const float*)d_in[19];
  const float* Wsc = (const float*)d_in[20];
  const float* bsc = (const float*)d_in[21];
  float* out = (float*)d_out;

  float* ws = (float*)d_ws;
  float* qf0 = ws; ws += (size_t)NB * MM * 64;
  float* qf1 = ws; ws += (size_t)NB * MM * 32;
  float* qf2 = ws; ws += (size_t)NB * MM * 16;
  float* cf0 = ws; ws += (size_t)NB * MM * 64;
  float* cf1 = ws; ws += (size_t)NB * MM * 32;
  float* cf2 = ws; ws += (size_t)NB * MM * 16;
  float* hcat = ws; ws += (size_t)NB * 48 * 256;
  float* l0  = ws; ws += (size_t)NB * 256;
  unsigned short* packA = (unsigned short*)ws; ws += 5376;  // 3*7*64*8 bf16

  pack_w<<<42, 256, 0, stream>>>(cw1, packA);

  gcn_kernel<<<dim3(NB, 2), 256, 0, stream>>>(x_q, x_c, src_q, dst_q, src_c, dst_c,
      Wg0, bg0, Wg1, bg1, Wg2, bg2, qf0, qf1, qf2, cf0, cf1, cf2);

  simconv_kernel<<<dim3(NB, 3), 256, 0, stream>>>(qf0, qf1, qf2, cf0, cf1, cf2,
      cw0, cb0, cb1, packA, hcat);

  init_l0<<<NB, 256, 0, stream>>>(bl0, l0);
  lin0_kernel<<<dim3(8, 4, 8), 256, 0, stream>>>(hcat, Wl0, l0);
  head_kernel<<<NB, 64, 0, stream>>>(l0, Wl1, bl1, Wsc, bsc, out);
}

// Round 5
// 191.222 us; speedup vs baseline: 4.0075x; 1.4921x over previous
//
#include <hip/hip_runtime.h>
#include <math.h>

#define NB 512      // graph pairs
#define MM 64       // nodes per graph
#define EPGc 512    // edges per graph

typedef __attribute__((ext_vector_type(8))) short s16x8;
typedef __attribute__((ext_vector_type(4))) float f32x4;

__device__ __forceinline__ unsigned short f2bf(float f) {
  union { float f; unsigned int u; } c; c.f = f;
  unsigned int u = c.u;
  return (unsigned short)((u + 0x7FFFu + ((u >> 16) & 1u)) >> 16);   // RNE
}
__device__ __forceinline__ float bf2f(unsigned short h) {
  union { unsigned int u; float f; } c; c.u = ((unsigned int)h) << 16;
  return c.f;
}

// acc[j] += sum_kk a[kk] * b_kk[j]
__device__ __forceinline__ void fma4x4(float (&acc)[4], const float4 a,
    const float4 b0, const float4 b1, const float4 b2, const float4 b3)
{
  acc[0] = fmaf(a.x, b0.x, acc[0]); acc[0] = fmaf(a.y, b1.x, acc[0]);
  acc[0] = fmaf(a.z, b2.x, acc[0]); acc[0] = fmaf(a.w, b3.x, acc[0]);
  acc[1] = fmaf(a.x, b0.y, acc[1]); acc[1] = fmaf(a.y, b1.y, acc[1]);
  acc[1] = fmaf(a.z, b2.y, acc[1]); acc[1] = fmaf(a.w, b3.y, acc[1]);
  acc[2] = fmaf(a.x, b0.z, acc[2]); acc[2] = fmaf(a.y, b1.z, acc[2]);
  acc[2] = fmaf(a.z, b2.z, acc[2]); acc[2] = fmaf(a.w, b3.z, acc[2]);
  acc[3] = fmaf(a.x, b0.w, acc[3]); acc[3] = fmaf(a.y, b1.w, acc[3]);
  acc[3] = fmaf(a.z, b2.w, acc[3]); acc[3] = fmaf(a.w, b3.w, acc[3]);
}

// ----------------------------- GCN: dense-adjacency, register-tiled LDS GEMMs -----------------------------
template<int Fin, int Fout, bool RELU>
__device__ __forceinline__ void gcn_layer(
    const float* __restrict__ W, const float* __restrict__ bias,
    const float* sA, float* sh, float* st, float* sW,
    float* __restrict__ outG, int g, int tid)
{
  constexpr int SIN = Fin + 4;
  constexpr int SOUT = Fout + 4;
  constexpr int TPR = Fout / 4;
  constexpr int TR  = (Fout == 64) ? 4 : (Fout == 32 ? 2 : 1);
  const int n0 = (tid / TPR) * TR;
  const int f0 = (tid % TPR) * 4;

  for (int i = tid; i < Fin * Fout / 4; i += 256)
    *reinterpret_cast<float4*>(sW + i * 4) = *reinterpret_cast<const float4*>(W + i * 4);
  __syncthreads();

  {
    float acc[TR][4];
#pragma unroll
    for (int i = 0; i < TR; ++i) { acc[i][0] = 0; acc[i][1] = 0; acc[i][2] = 0; acc[i][3] = 0; }
#pragma unroll
    for (int k = 0; k < Fin; k += 4) {
      float4 b0 = *reinterpret_cast<const float4*>(sW + (k + 0) * Fout + f0);
      float4 b1 = *reinterpret_cast<const float4*>(sW + (k + 1) * Fout + f0);
      float4 b2 = *reinterpret_cast<const float4*>(sW + (k + 2) * Fout + f0);
      float4 b3 = *reinterpret_cast<const float4*>(sW + (k + 3) * Fout + f0);
#pragma unroll
      for (int i = 0; i < TR; ++i) {
        float4 a = *reinterpret_cast<const float4*>(sh + (n0 + i) * SIN + k);
        fma4x4(acc[i], a, b0, b1, b2, b3);
      }
    }
#pragma unroll
    for (int i = 0; i < TR; ++i)
      *reinterpret_cast<float4*>(st + (n0 + i) * Fout + f0) =
          make_float4(acc[i][0], acc[i][1], acc[i][2], acc[i][3]);
  }
  __syncthreads();

  {
    float acc[TR][4];
#pragma unroll
    for (int i = 0; i < TR; ++i) { acc[i][0] = 0; acc[i][1] = 0; acc[i][2] = 0; acc[i][3] = 0; }
#pragma unroll
    for (int k = 0; k < 64; k += 4) {
      float4 b0 = *reinterpret_cast<const float4*>(st + (k + 0) * Fout + f0);
      float4 b1 = *reinterpret_cast<const float4*>(st + (k + 1) * Fout + f0);
      float4 b2 = *reinterpret_cast<const float4*>(st + (k + 2) * Fout + f0);
      float4 b3 = *reinterpret_cast<const float4*>(st + (k + 3) * Fout + f0);
#pragma unroll
      for (int i = 0; i < TR; ++i) {
        float4 a = *reinterpret_cast<const float4*>(sA + (n0 + i) * 68 + k);
        fma4x4(acc[i], a, b0, b1, b2, b3);
      }
    }
    float4 bv = *reinterpret_cast<const float4*>(bias + f0);
#pragma unroll
    for (int i = 0; i < TR; ++i) {
      float4 v = make_float4(acc[i][0] + bv.x, acc[i][1] + bv.y,
                             acc[i][2] + bv.z, acc[i][3] + bv.w);
      *reinterpret_cast<float4*>(outG + ((size_t)(g * MM + n0 + i) * Fout) + f0) = v;
      float4 r = RELU ? make_float4(fmaxf(v.x, 0.f), fmaxf(v.y, 0.f),
                                    fmaxf(v.z, 0.f), fmaxf(v.w, 0.f)) : v;
      *reinterpret_cast<float4*>(sh + (n0 + i) * SOUT + f0) = r;
    }
  }
  __syncthreads();
}

__global__ __launch_bounds__(256) void gcn_kernel(
    const float* __restrict__ xq, const float* __restrict__ xc,
    const int* __restrict__ srcq, const int* __restrict__ dstq,
    const int* __restrict__ srcc, const int* __restrict__ dstc,
    const float* __restrict__ Wg0, const float* __restrict__ bg0,
    const float* __restrict__ Wg1, const float* __restrict__ bg1,
    const float* __restrict__ Wg2, const float* __restrict__ bg2,
    float* __restrict__ qf0, float* __restrict__ qf1, float* __restrict__ qf2,
    float* __restrict__ cf0, float* __restrict__ cf1, float* __restrict__ cf2)
{
  __shared__ __align__(16) float sA[64 * 68];
  __shared__ __align__(16) float sh[64 * 68];
  __shared__ __align__(16) float st[64 * 64];
  __shared__ __align__(16) float sW[2048];
  __shared__ float sDinv[MM];
  __shared__ int sDeg[MM];

  const int g = blockIdx.x;
  const int which = blockIdx.y;
  const float* x = which ? xc : xq;
  const int* src = which ? srcc : srcq;
  const int* dst = which ? dstc : dstq;
  float* f0p = which ? cf0 : qf0;
  float* f1p = which ? cf1 : qf1;
  float* f2p = which ? cf2 : qf2;
  const int tid = threadIdx.x;

  for (int i = tid; i < 64 * 68; i += 256) sA[i] = 0.f;
  if (tid < MM) sDeg[tid] = 1;
  __syncthreads();
  for (int e = tid; e < EPGc; e += 256)
    atomicAdd(&sDeg[dst[g * EPGc + e] - g * MM], 1);
  __syncthreads();
  if (tid < MM) sDinv[tid] = rsqrtf((float)sDeg[tid]);
  __syncthreads();
  for (int e = tid; e < EPGc; e += 256) {
    int s = src[g * EPGc + e] - g * MM;
    int d = dst[g * EPGc + e] - g * MM;
    atomicAdd(&sA[d * 68 + s], sDinv[s] * sDinv[d]);
  }
  if (tid < MM) atomicAdd(&sA[tid * 68 + tid], sDinv[tid] * sDinv[tid]);
  for (int i = tid; i < 512; i += 256) {
    float4 v = *reinterpret_cast<const float4*>(x + (size_t)g * 2048 + i * 4);
    int n = (i * 4) >> 5, k = (i * 4) & 31;
    *reinterpret_cast<float4*>(sh + n * 36 + k) = v;
  }
  __syncthreads();

  gcn_layer<32, 64, true >(Wg0, bg0, sA, sh, st, sW, f0p, g, tid);
  gcn_layer<64, 32, true >(Wg1, bg1, sA, sh, st, sW, f1p, g, tid);
  gcn_layer<32, 16, false>(Wg2, bg2, sA, sh, st, sW, f2p, g, tid);
}

// ----------------------------- conv2 weight prepack: A-fragment layout per lane -----------------------------
// packA[((lvl*7+g)*64 + lane)*8 + j] = W[oc=lane&15][k=g*32 + (lane>>4)*8 + j], k=(shift s, ic j), s=g*4+(lane>>4)
__global__ __launch_bounds__(256) void pack_w(const float* __restrict__ cw1,
                                              unsigned short* __restrict__ packA)
{
  int i = blockIdx.x * 256 + threadIdx.x;
  if (i >= 3 * 7 * 64 * 8) return;
  int j = i & 7, l = (i >> 3) & 63, g = (i >> 9) % 7, lvl = i / 3584;
  int oc = l & 15, sg = l >> 4;
  int s = g * 4 + sg;
  float v = 0.f;
  if (s < 25) v = cw1[((size_t)(lvl * 16 + oc) * 8 + j) * 25 + s];
  packA[i] = f2bf(v);
}

// ----------------------------- Wl0 prepack: bf16, transposed to [n][k] -----------------------------
__global__ __launch_bounds__(256) void pack_wl0(const float* __restrict__ Wl0,
                                                unsigned short* __restrict__ WT)
{
  __shared__ float tile[64][65];
  const int kb = blockIdx.x * 64;    // 192 blocks
  const int nb = blockIdx.y * 64;    // 4 blocks
  const int tid = threadIdx.x;
#pragma unroll
  for (int i = 0; i < 16; ++i) {
    int idx = i * 256 + tid, kk = idx >> 6, nn = idx & 63;
    tile[kk][nn] = Wl0[(size_t)(kb + kk) * 256 + nb + nn];   // coalesced in n
  }
  __syncthreads();
#pragma unroll
  for (int i = 0; i < 16; ++i) {
    int idx = i * 256 + tid, nn = idx >> 6, kk = idx & 63;
    WT[(size_t)(nb + nn) * 12288 + kb + kk] = f2bf(tile[kk][nn]);  // coalesced in k
  }
}

// ----------------------------- fused sim + conv1 + conv2(MFMA) + pool -----------------------------
template<int F>
__device__ __forceinline__ void sim_compute(const float* __restrict__ qf,
    const float* __restrict__ cf, float* sq, float* scT, float* ssim, int g, int tid)
{
  for (int i = tid; i < 64 * F / 4; i += 256) {
    float4 v = *reinterpret_cast<const float4*>(qf + (size_t)g * 64 * F + i * 4);
    int n = (i * 4) / F, f = (i * 4) % F;
    *reinterpret_cast<float4*>(sq + n * 68 + f) = v;
  }
  for (int i = tid; i < 64 * F / 4; i += 256) {
    float4 v = *reinterpret_cast<const float4*>(cf + (size_t)g * 64 * F + i * 4);
    int n = (i * 4) / F, f = (i * 4) % F;
    scT[(f + 0) * 68 + n] = v.x; scT[(f + 1) * 68 + n] = v.y;
    scT[(f + 2) * 68 + n] = v.z; scT[(f + 3) * 68 + n] = v.w;
  }
  for (int i = tid; i < 68 * 68; i += 256) ssim[i] = 0.f;
  __syncthreads();

  const int tm = (tid >> 4) << 2;
  const int tn = (tid & 15) << 2;
  float acc[4][4];
#pragma unroll
  for (int i = 0; i < 4; ++i) { acc[i][0] = 0; acc[i][1] = 0; acc[i][2] = 0; acc[i][3] = 0; }
#pragma unroll
  for (int k = 0; k < F; k += 4) {
    float4 c0 = *reinterpret_cast<const float4*>(scT + (k + 0) * 68 + tn);
    float4 c1 = *reinterpret_cast<const float4*>(scT + (k + 1) * 68 + tn);
    float4 c2 = *reinterpret_cast<const float4*>(scT + (k + 2) * 68 + tn);
    float4 c3 = *reinterpret_cast<const float4*>(scT + (k + 3) * 68 + tn);
#pragma unroll
    for (int i = 0; i < 4; ++i) {
      float4 a = *reinterpret_cast<const float4*>(sq + (tm + i) * 68 + k);
      fma4x4(acc[i], a, c0, c1, c2, c3);
    }
  }
#pragma unroll
  for (int i = 0; i < 4; ++i)
#pragma unroll
    for (int j = 0; j < 4; ++j)
      ssim[(tm + i + 2) * 68 + (tn + j + 2)] = acc[i][j];
  __syncthreads();
}

// conv1 (fp32 VALU) -> pool -> bias -> relu -> bf16 channel-interleaved p1ci[36][36][8]
__device__ __forceinline__ void conv1_compute(const float* ssim, unsigned short* p1u,
    const float* __restrict__ w, const float* __restrict__ bb, int tid)
{
  // zero the halo frame: 272 cells > 256 threads -> strided loop
  for (int h = tid; h < 272; h += 256) {
    int r, c;
    if (h < 72)       { r = h / 36;             c = h % 36; }
    else if (h < 144) { r = 34 + (h - 72) / 36; c = (h - 72) % 36; }
    else { int z = h - 144; r = 2 + (z >> 2); int wq = z & 3; c = (wq < 2) ? wq : 32 + wq; }
    s16x8 zz = {0, 0, 0, 0, 0, 0, 0, 0};
    *reinterpret_cast<s16x8*>(p1u + (r * 36 + c) * 8) = zz;
  }

  for (int it = 0; it < 4; ++it) {
    int pos = tid + (it << 8);
    int y = pos >> 5, x = pos & 31;
    float win[6][6];
#pragma unroll
    for (int u = 0; u < 6; ++u)
#pragma unroll
      for (int v = 0; v < 6; ++v) win[u][v] = ssim[(2 * y + u) * 68 + (2 * x + v)];
    float acc[8][4];
#pragma unroll
    for (int c = 0; c < 8; ++c) { acc[c][0] = 0; acc[c][1] = 0; acc[c][2] = 0; acc[c][3] = 0; }
#pragma unroll
    for (int u = 0; u < 5; ++u)
#pragma unroll
      for (int v = 0; v < 5; ++v) {
#pragma unroll
        for (int c = 0; c < 8; ++c) {
          float wt = w[c * 25 + u * 5 + v];
          acc[c][0] = fmaf(win[u][v],         wt, acc[c][0]);
          acc[c][1] = fmaf(win[u][v + 1],     wt, acc[c][1]);
          acc[c][2] = fmaf(win[u + 1][v],     wt, acc[c][2]);
          acc[c][3] = fmaf(win[u + 1][v + 1], wt, acc[c][3]);
        }
      }
    s16x8 pk;
#pragma unroll
    for (int c = 0; c < 8; ++c) {
      float mx = fmaxf(fmaxf(acc[c][0], acc[c][1]), fmaxf(acc[c][2], acc[c][3])) + bb[c];
      pk[c] = (short)f2bf(fmaxf(mx, 0.f));
    }
    *reinterpret_cast<s16x8*>(p1u + ((y + 2) * 36 + (x + 2)) * 8) = pk;
  }
  __syncthreads();
}

__global__ __launch_bounds__(256) void simconv_kernel(
    const float* __restrict__ qf0, const float* __restrict__ qf1, const float* __restrict__ qf2,
    const float* __restrict__ cf0, const float* __restrict__ cf1, const float* __restrict__ cf2,
    const float* __restrict__ cw0, const float* __restrict__ cb0,
    const float* __restrict__ cb1, const unsigned short* __restrict__ packA,
    float* __restrict__ hcat)
{
  __shared__ __align__(16) float smem[13440];   // 53760 B -> 3 blocks/CU
  float* sq   = smem;
  float* scT  = smem + 4352;
  float* ssim = smem + 8704;
  unsigned short* p1u = reinterpret_cast<unsigned short*>(smem);
  unsigned short* c2u = reinterpret_cast<unsigned short*>(smem + 5248);

  const int g = blockIdx.x, lvl = blockIdx.y, tid = threadIdx.x;

  if (lvl == 0)      sim_compute<64>(qf0, cf0, sq, scT, ssim, g, tid);
  else if (lvl == 1) sim_compute<32>(qf1, cf1, sq, scT, ssim, g, tid);
  else               sim_compute<16>(qf2, cf2, sq, scT, ssim, g, tid);

  conv1_compute(ssim, p1u, cw0 + lvl * 200, cb0 + lvl * 8, tid);

  // ---- conv2 via MFMA: out[16 oc][1024 pix], K = 7 groups x 32 (shift s = gg*4+(l>>4), ic = j) ----
  {
    const int lane = tid & 63, wave = tid >> 6;
    const int col = lane & 15, q = lane >> 4;

    s16x8 afr[7];
#pragma unroll
    for (int gg = 0; gg < 7; ++gg)
      afr[gg] = *reinterpret_cast<const s16x8*>(packA + ((size_t)(lvl * 7 + gg) * 64 + lane) * 8);

    int off[7];
#pragma unroll
    for (int gg = 0; gg < 7; ++gg) {
      int s = gg * 4 + q; if (s > 24) s = 24;
      off[gg] = (s / 5) * 288 + (s % 5) * 8;
    }

    for (int tt = 0; tt < 16; ++tt) {
      int t = wave * 16 + tt;
      int base = (t >> 1) * 288 + (t & 1) * 128 + col * 8;
      f32x4 acc = {0.f, 0.f, 0.f, 0.f};
#pragma unroll
      for (int gg = 0; gg < 7; ++gg) {
        s16x8 b = *reinterpret_cast<const s16x8*>(p1u + base + off[gg]);
        acc = __builtin_amdgcn_mfma_f32_16x16x32_bf16(afr[gg], b, acc, 0, 0, 0);
      }
      int pix = t * 16 + col;
      unsigned short pk[4];
#pragma unroll
      for (int r = 0; r < 4; ++r) pk[r] = f2bf(acc[r]);
      unsigned int w0 = (unsigned int)pk[0] | ((unsigned int)pk[1] << 16);
      unsigned int w1 = (unsigned int)pk[2] | ((unsigned int)pk[3] << 16);
      uint2 dw = make_uint2(w0, w1);
      *reinterpret_cast<uint2*>(c2u + pix * 16 + q * 4) = dw;
    }
  }
  __syncthreads();

  // ---- pool 2x2 + bias + relu -> hcat ----
  {
    const float* bb = cb1 + lvl * 16;
#pragma unroll
    for (int m = 0; m < 4; ++m) {
      int u = m * 256 + tid;
      int q = u & 3, p = u >> 2;
      int py = p >> 4, px = p & 15;
      float best[4] = {-1e30f, -1e30f, -1e30f, -1e30f};
#pragma unroll
      for (int dy = 0; dy < 2; ++dy)
#pragma unroll
        for (int dx = 0; dx < 2; ++dx) {
          uint2 dv = *reinterpret_cast<const uint2*>(
              c2u + (((2 * py + dy) * 32 + 2 * px + dx) * 16 + q * 4));
          best[0] = fmaxf(best[0], bf2f((unsigned short)(dv.x & 0xFFFF)));
          best[1] = fmaxf(best[1], bf2f((unsigned short)(dv.x >> 16)));
          best[2] = fmaxf(best[2], bf2f((unsigned short)(dv.y & 0xFFFF)));
          best[3] = fmaxf(best[3], bf2f((unsigned short)(dv.y >> 16)));
        }
#pragma unroll
      for (int r = 0; r < 4; ++r) {
        int oc = q * 4 + r;
        float val = fmaxf(best[r] + bb[oc], 0.f);
        hcat[((size_t)g * 48 + lvl * 16 + oc) * 256 + p] = val;
      }
    }
  }
}

// ----------------------------- linear 0 via MFMA: (512,12288)bf16 @ (12288,256)bf16, split-K -----------------------------
__global__ __launch_bounds__(256) void init_l0(const float* __restrict__ bl0, float* __restrict__ l0)
{
  int i = blockIdx.x * 256 + threadIdx.x;
  l0[i] = bl0[i & 255];
}

// grid (8 Mblk, 4 Nblk, 16 Ksplit); block 256 = 4 waves (2x2 of 32x32)
__global__ __launch_bounds__(256) void lin0_kernel(
    const float* __restrict__ A, const unsigned short* __restrict__ WT,
    float* __restrict__ l0)
{
  __shared__ __align__(16) unsigned short sAb[64 * 72];  // rows m, padded k-stride 72
  __shared__ __align__(16) unsigned short sBb[64 * 72];  // rows n, padded k-stride 72
  const int rb = blockIdx.x * 64;
  const int cb = blockIdx.y * 64;
  const int k0 = blockIdx.z * 768;      // 12 K-steps of 64
  const int tid = threadIdx.x;
  const int lane = tid & 63, wave = tid >> 6;
  const int wm = wave >> 1, wn = wave & 1;
  const int c = lane & 15, kg = lane >> 4;

  // staging indices: 4 threads per row, 16 k each
  const int srow = tid >> 2;
  const int skq  = (tid & 3) * 16;

  f32x4 acc[2][2];
#pragma unroll
  for (int i = 0; i < 2; ++i)
#pragma unroll
    for (int j = 0; j < 2; ++j) acc[i][j] = (f32x4){0.f, 0.f, 0.f, 0.f};

  for (int kt = 0; kt < 768; kt += 64) {
    // A: fp32 -> bf16 LDS
    {
      const float* src = A + (size_t)(rb + srow) * 12288 + k0 + kt + skq;
      float4 v0 = *reinterpret_cast<const float4*>(src + 0);
      float4 v1 = *reinterpret_cast<const float4*>(src + 4);
      float4 v2 = *reinterpret_cast<const float4*>(src + 8);
      float4 v3 = *reinterpret_cast<const float4*>(src + 12);
      s16x8 p0, p1;
      p0[0] = (short)f2bf(v0.x); p0[1] = (short)f2bf(v0.y); p0[2] = (short)f2bf(v0.z); p0[3] = (short)f2bf(v0.w);
      p0[4] = (short)f2bf(v1.x); p0[5] = (short)f2bf(v1.y); p0[6] = (short)f2bf(v1.z); p0[7] = (short)f2bf(v1.w);
      p1[0] = (short)f2bf(v2.x); p1[1] = (short)f2bf(v2.y); p1[2] = (short)f2bf(v2.z); p1[3] = (short)f2bf(v2.w);
      p1[4] = (short)f2bf(v3.x); p1[5] = (short)f2bf(v3.y); p1[6] = (short)f2bf(v3.z); p1[7] = (short)f2bf(v3.w);
      *reinterpret_cast<s16x8*>(sAb + srow * 72 + skq)     = p0;
      *reinterpret_cast<s16x8*>(sAb + srow * 72 + skq + 8) = p1;
    }
    // B: bf16 copy
    {
      const unsigned short* src = WT + (size_t)(cb + srow) * 12288 + k0 + kt + skq;
      s16x8 w0 = *reinterpret_cast<const s16x8*>(src);
      s16x8 w1 = *reinterpret_cast<const s16x8*>(src + 8);
      *reinterpret_cast<s16x8*>(sBb + srow * 72 + skq)     = w0;
      *reinterpret_cast<s16x8*>(sBb + srow * 72 + skq + 8) = w1;
    }
    __syncthreads();

#pragma unroll
    for (int kb = 0; kb < 64; kb += 32) {
      s16x8 a0 = *reinterpret_cast<const s16x8*>(sAb + (wm * 32 +  0 + c) * 72 + kb + kg * 8);
      s16x8 a1 = *reinterpret_cast<const s16x8*>(sAb + (wm * 32 + 16 + c) * 72 + kb + kg * 8);
      s16x8 b0 = *reinterpret_cast<const s16x8*>(sBb + (wn * 32 +  0 + c) * 72 + kb + kg * 8);
      s16x8 b1 = *reinterpret_cast<const s16x8*>(sBb + (wn * 32 + 16 + c) * 72 + kb + kg * 8);
      acc[0][0] = __builtin_amdgcn_mfma_f32_16x16x32_bf16(a0, b0, acc[0][0], 0, 0, 0);
      acc[0][1] = __builtin_amdgcn_mfma_f32_16x16x32_bf16(a0, b1, acc[0][1], 0, 0, 0);
      acc[1][0] = __builtin_amdgcn_mfma_f32_16x16x32_bf16(a1, b0, acc[1][0], 0, 0, 0);
      acc[1][1] = __builtin_amdgcn_mfma_f32_16x16x32_bf16(a1, b1, acc[1][1], 0, 0, 0);
    }
    __syncthreads();
  }

  // D: col = lane&15, row = (lane>>4)*4 + r
#pragma unroll
  for (int i = 0; i < 2; ++i)
#pragma unroll
    for (int j = 0; j < 2; ++j)
#pragma unroll
      for (int r = 0; r < 4; ++r) {
        int row = rb + wm * 32 + i * 16 + kg * 4 + r;
        int col = cb + wn * 32 + j * 16 + c;
        atomicAdd(&l0[(size_t)row * 256 + col], acc[i][j][r]);
      }
}

// ----------------------------- head -----------------------------
__global__ __launch_bounds__(64) void head_kernel(
    const float* __restrict__ l0, const float* __restrict__ Wl1, const float* __restrict__ bl1,
    const float* __restrict__ Wsc, const float* __restrict__ bsc, float* __restrict__ out)
{
  __shared__ float sr[256];
  const int b = blockIdx.x, j = threadIdx.x;
  for (int k = j; k < 256; k += 64) sr[k] = fmaxf(l0[(size_t)b * 256 + k], 0.f);
  __syncthreads();
  float acc = bl1[j];
  for (int k = 0; k < 256; ++k) acc = fmaf(sr[k], Wl1[k * 64 + j], acc);
  float v = fmaxf(acc, 0.f) * Wsc[j];
#pragma unroll
  for (int off = 32; off > 0; off >>= 1) v += __shfl_down(v, off);
  if (j == 0) out[b] = 1.f / (1.f + expf(-(v + bsc[0])));
}

// ----------------------------- launch -----------------------------
extern "C" void kernel_launch(void* const* d_in, const int* in_sizes, int n_in,
                              void* d_out, int out_size, void* d_ws, size_t ws_size,
                              hipStream_t stream)
{
  (void)in_sizes; (void)n_in; (void)out_size; (void)ws_size;
  const float* x_q = (const float*)d_in[0];
  const float* x_c = (const float*)d_in[1];
  const int*   src_q = (const int*)d_in[2];
  const int*   dst_q = (const int*)d_in[3];
  const int*   src_c = (const int*)d_in[4];
  const int*   dst_c = (const int*)d_in[5];
  const float* Wg0 = (const float*)d_in[6];
  const float* bg0 = (const float*)d_in[7];
  const float* Wg1 = (const float*)d_in[8];
  const float* bg1 = (const float*)d_in[9];
  const float* Wg2 = (const float*)d_in[10];
  const float* bg2 = (const float*)d_in[11];
  const float* cw0 = (const float*)d_in[12];
  const float* cb0 = (const float*)d_in[13];
  const float* cw1 = (const float*)d_in[14];
  const float* cb1 = (const float*)d_in[15];
  const float* Wl0 = (const float*)d_in[16];
  const float* bl0 = (const float*)d_in[17];
  const float* Wl1 = (const float*)d_in[18];
  const float* bl1 = (const float*)d_in[19];
  const float* Wsc = (const float*)d_in[20];
  const float* bsc = (const float*)d_in[21];
  float* out = (float*)d_out;

  float* ws = (float*)d_ws;
  float* qf0 = ws; ws += (size_t)NB * MM * 64;
  float* qf1 = ws; ws += (size_t)NB * MM * 32;
  float* qf2 = ws; ws += (size_t)NB * MM * 16;
  float* cf0 = ws; ws += (size_t)NB * MM * 64;
  float* cf1 = ws; ws += (size_t)NB * MM * 32;
  float* cf2 = ws; ws += (size_t)NB * MM * 16;
  float* hcat = ws; ws += (size_t)NB * 48 * 256;
  float* l0  = ws; ws += (size_t)NB * 256;
  unsigned short* packA = (unsigned short*)ws; ws += 5376;   // 3*7*64*8 bf16 (padded to float-mult)
  unsigned short* WT = (unsigned short*)ws; ws += (size_t)256 * 12288 / 2;  // 6.3 MB bf16 [n][k]

  pack_w<<<42, 256, 0, stream>>>(cw1, packA);
  pack_wl0<<<dim3(192, 4), 256, 0, stream>>>(Wl0, WT);

  gcn_kernel<<<dim3(NB, 2), 256, 0, stream>>>(x_q, x_c, src_q, dst_q, src_c, dst_c,
      Wg0, bg0, Wg1, bg1, Wg2, bg2, qf0, qf1, qf2, cf0, cf1, cf2);

  simconv_kernel<<<dim3(NB, 3), 256, 0, stream>>>(qf0, qf1, qf2, cf0, cf1, cf2,
      cw0, cb0, cb1, packA, hcat);

  init_l0<<<NB, 256, 0, stream>>>(bl0, l0);
  lin0_kernel<<<dim3(8, 4, 16), 256, 0, stream>>>(hcat, WT, l0);
  head_kernel<<<NB, 64, 0, stream>>>(l0, Wl1, bl1, Wsc, bsc, out);
}